// Round 6
// baseline (346.721 us; speedup 1.0000x reference)
//
#include <hip/hip_runtime.h>
#include <cstdint>
#include <cstddef>

// RNNDec GRU rollout: N=4096, H=512, T=12. R6 = R5 + (a) x_t computed locally
// per block from the staged A tile (out = W_out . h_t) -- removes the partial
// exchange machinery entirely; (b) vectorized k0; (c) k3 = direct dot.
// Core: 32x32x16 f16 MFMA, fp16 h state + fp16 gi planes (absmax 0.0078 in R5).

typedef __attribute__((ext_vector_type(8))) _Float16 f16x8;
typedef __attribute__((ext_vector_type(4))) _Float16 f16x4;
typedef __attribute__((ext_vector_type(16))) float floatx16;

__device__ __forceinline__ float sigm_f(float v) { return 1.0f / (1.0f + __expf(-v)); }
__device__ __forceinline__ float tanh_f(float v) { return 2.0f / (1.0f + __expf(-2.0f * v)) - 1.0f; }

__device__ __forceinline__ void async16(void* lds, const void* g) {
    __builtin_amdgcn_global_load_lds(
        (const __attribute__((address_space(1))) void*)g,
        (__attribute__((address_space(3))) void*)lds, 16, 0, 0);
}

// ---------------- K0: casts + packing + a0 (vectorized) ----------------
__global__ __launch_bounds__(256) void k0_prep(
    const float* __restrict__ z, const float* __restrict__ x,
    const float* __restrict__ x0, const float* __restrict__ W_ia,
    const float* __restrict__ b_ia, const float* __restrict__ W_ih,
    const float* __restrict__ W_hh, const float* __restrict__ W_h0,
    const float* __restrict__ W_out, const float* __restrict__ b_hh,
    _Float16* __restrict__ zx16, _Float16* __restrict__ wcat16,
    _Float16* __restrict__ whh16, float* __restrict__ pk, float* __restrict__ xbuf)
{
    const int ZXV = 262144;            // 4096*256/4
    const int WCV = 131072;            // 2048*256/4
    const int WHV = 196608;            // 1536*512/4
    const int PKN = 512, XB = 8192;
    const int TOT = ZXV + WCV + WHV + PKN + XB;
    for (int g = blockIdx.x * 256 + threadIdx.x; g < TOT; g += gridDim.x * 256) {
        if (g < ZXV) {
            int i = g >> 6, k = (g & 63) << 2;
            float4 v = (k < 128) ? *(const float4*)(z + (size_t)i * 128 + k)
                                 : *(const float4*)(x + (size_t)i * 128 + (k - 128));
            f16x4 o = {(_Float16)v.x, (_Float16)v.y, (_Float16)v.z, (_Float16)v.w};
            *(f16x4*)(zx16 + (size_t)g * 4) = o;
        } else if (g < ZXV + WCV) {
            int j = (g - ZXV) << 2;
            int n = j >> 8, k = j & 255;
            float4 v;
            if (n < 512) {
                v = *(const float4*)(W_h0 + (size_t)n * 256 + k);
            } else {
                const float* p = W_ih + (size_t)(n - 512) * 258 + k;
                float2 a = *(const float2*)p, b = *(const float2*)(p + 2);
                v = make_float4(a.x, a.y, b.x, b.y);
            }
            f16x4 o = {(_Float16)v.x, (_Float16)v.y, (_Float16)v.z, (_Float16)v.w};
            *(f16x4*)(wcat16 + (size_t)j) = o;
        } else if (g < ZXV + WCV + WHV) {
            int j = (g - ZXV - WCV) << 2;
            float4 v = *(const float4*)(W_hh + (size_t)j);
            f16x4 o = {(_Float16)v.x, (_Float16)v.y, (_Float16)v.z, (_Float16)v.w};
            *(f16x4*)(whh16 + (size_t)j) = o;
        } else if (g < ZXV + WCV + WHV + PKN) {
            int jc = g - ZXV - WCV - WHV;
            float* o = pk + jc * 12;
            o[0] = W_ih[jc * 258 + 256];          o[1] = W_ih[jc * 258 + 257];
            o[2] = W_ih[(512 + jc) * 258 + 256];  o[3] = W_ih[(512 + jc) * 258 + 257];
            o[4] = W_ih[(1024 + jc) * 258 + 256]; o[5] = W_ih[(1024 + jc) * 258 + 257];
            o[6] = b_hh[jc]; o[7] = b_hh[512 + jc]; o[8] = b_hh[1024 + jc];
            o[9] = 0.f; o[10] = 0.f; o[11] = 0.f;
        } else {
            int j = g - ZXV - WCV - WHV - PKN;
            int i = j >> 1, d = j & 1;
            float s = b_ia[d];
            #pragma unroll
            for (int k2 = 0; k2 < 4; k2++) s += x0[i * 4 + k2] * W_ia[d * 4 + k2];
            xbuf[j] = s;
        }
    }
}

// ---------------- K1: h0 (cols 0..511) + gi planes (cols 512..2047), fp16 ----------------
__global__ __launch_bounds__(256) void k1_precompute(
    const _Float16* __restrict__ zx16, const _Float16* __restrict__ wcat16,
    const float* __restrict__ b_h0, const float* __restrict__ b_ih,
    _Float16* __restrict__ h16a, _Float16* __restrict__ gi16)
{
    __shared__ __align__(16) char smem[24576];
    const uint32_t BOFF = 0, AOFF = 8192;
    int tid = threadIdx.x;
    int w = tid >> 6, lane = tid & 63;
    int half = lane >> 5, l31 = lane & 31;
    int rsub = lane >> 3, csub = lane & 7;
    int Mb = blockIdx.x * 128, Nb = blockIdx.y * 64;

    const _Float16* gsrc[6];
    uint32_t ldso[6];
    #pragma unroll
    for (int j = 0; j < 6; j++) {
        int L = w + 4 * j;
        if (L < 16) {
            int r = L * 8 + rsub;
            gsrc[j] = zx16 + (size_t)(Mb + r) * 256 + ((csub ^ (r & 7)) << 3);
            ldso[j] = AOFF + (uint32_t)L * 1024;
        } else {
            int rb = (L - 16) * 8 + rsub;
            gsrc[j] = wcat16 + (size_t)(Nb + rb) * 256 + ((csub ^ (rb & 7)) << 3);
            ldso[j] = BOFF + (uint32_t)(L - 16) * 1024;
        }
    }

    floatx16 acc0 = {0,0,0,0,0,0,0,0,0,0,0,0,0,0,0,0};
    floatx16 acc1 = {0,0,0,0,0,0,0,0,0,0,0,0,0,0,0,0};

    for (int kc = 0; kc < 4; kc++) {
        #pragma unroll
        for (int j = 0; j < 6; j++) async16(smem + ldso[j], gsrc[j] + kc * 64);
        __syncthreads();
        #pragma unroll
        for (int ks = 0; ks < 4; ks++) {
            int ch = ks * 2 + half;
            int ar = (w << 5) | l31;
            f16x8 a = *(const f16x8*)(smem + AOFF + ((uint32_t)ar << 7) + ((uint32_t)(ch ^ (ar & 7)) << 4));
            uint32_t sw = (uint32_t)(ch ^ (l31 & 7)) << 4;
            f16x8 b0 = *(const f16x8*)(smem + BOFF + ((uint32_t)l31 << 7) + sw);
            f16x8 b1 = *(const f16x8*)(smem + BOFF + ((uint32_t)(32 + l31) << 7) + sw);
            acc0 = __builtin_amdgcn_mfma_f32_32x32x16_f16(a, b0, acc0, 0, 0, 0);
            acc1 = __builtin_amdgcn_mfma_f32_32x32x16_f16(a, b1, acc1, 0, 0, 0);
        }
        __syncthreads();
    }

    #pragma unroll
    for (int nt = 0; nt < 2; nt++) {
        int ncol = Nb + nt * 32 + l31;
        floatx16 acc = nt ? acc1 : acc0;
        #pragma unroll
        for (int reg = 0; reg < 16; reg++) {
            int row = (reg & 3) + 8 * (reg >> 2) + 4 * half;
            size_t i = (size_t)Mb + (w << 5) + row;
            float v = acc[reg];
            if (ncol < 512) {
                h16a[i * 512 + ncol] = (_Float16)(v + b_h0[ncol]);
            } else {
                int c = ncol - 512;
                int g = c >> 9, jc = c & 511;
                gi16[(size_t)g * 2097152 + i * 512 + jc] = (_Float16)(v + b_ih[c]);
            }
        }
    }
}

// ---------------- K2: one GRU step ----------------
// Tile 128m x (32 jc x 3 gates). grid (32,16), 256 thr = 4 waves.
// x_t computed locally: thread (row=tid>>1, d=tid&1) dots the staged A chunks
// against LDS-resident W_out plane -> no cross-block partial exchange.
__global__ __launch_bounds__(256, 2) void k2_step(
    int t,
    const _Float16* __restrict__ hin, _Float16* __restrict__ hout,
    const _Float16* __restrict__ whh16, const _Float16* __restrict__ gi16,
    const float* __restrict__ pk, const float* __restrict__ xbuf,
    const float* __restrict__ W_out, const float* __restrict__ b_out,
    float* __restrict__ dout)
{
    __shared__ __align__(16) char smem[33792];
    const uint32_t BOFF = 0, AOFF = 12288, WOUT = 28672, XS = 32768;
    int tid = threadIdx.x;
    int bx = blockIdx.x, by = blockIdx.y;
    int Mbase = bx * 128, Jbase = by * 32;
    int w = tid >> 6, lane = tid & 63;
    int half = lane >> 5, l31 = lane & 31;
    int rsub = lane >> 3, csub = lane & 7;
    float* xs = (float*)(smem + XS);  // [128][2]

    // stage W_out (2 planes x 512 fp32 = 4 KB) into LDS
    async16(smem + WOUT + (uint32_t)w * 1024, W_out + w * 256 + lane * 4);

    // A/B staging: A = 16 slots of 8 rows x 64 fp16; B = 12 slots (96 rows)
    const _Float16* gsrc[7];
    uint32_t ldso[7];
    #pragma unroll
    for (int j = 0; j < 7; j++) {
        int L = w + 4 * j;   // 0..27
        if (L < 16) {
            int r = L * 8 + rsub;
            gsrc[j] = hin + (size_t)(Mbase + r) * 512 + ((csub ^ (r & 7)) << 3);
            ldso[j] = AOFF + (uint32_t)L * 1024;
        } else {
            int rb = (L - 16) * 8 + rsub;   // 0..95: rb = g*32 + jin
            int g = rb >> 5, jin = rb & 31;
            gsrc[j] = whh16 + (size_t)(g * 512 + Jbase + jin) * 512 + ((csub ^ (rb & 7)) << 3);
            ldso[j] = BOFF + (uint32_t)(L - 16) * 1024;
        }
    }

    int xrow = tid >> 1, xd = tid & 1;
    float bo = b_out[xd];
    float xacc = 0.f;

    floatx16 accR = {0,0,0,0,0,0,0,0,0,0,0,0,0,0,0,0};
    floatx16 accZ = {0,0,0,0,0,0,0,0,0,0,0,0,0,0,0,0};
    floatx16 accN = {0,0,0,0,0,0,0,0,0,0,0,0,0,0,0,0};

    for (int kc = 0; kc < 8; kc++) {
        #pragma unroll
        for (int j = 0; j < 7; j++) async16(smem + ldso[j], gsrc[j] + kc * 64);
        __syncthreads();
        #pragma unroll
        for (int ks = 0; ks < 4; ks++) {
            int ch = ks * 2 + half;
            int ar = (w << 5) | l31;
            f16x8 a = *(const f16x8*)(smem + AOFF + ((uint32_t)ar << 7) + ((uint32_t)(ch ^ (ar & 7)) << 4));
            uint32_t sw = (uint32_t)(ch ^ (l31 & 7)) << 4;
            f16x8 b0 = *(const f16x8*)(smem + BOFF + ((uint32_t)l31 << 7) + sw);
            f16x8 b1 = *(const f16x8*)(smem + BOFF + ((uint32_t)(32 + l31) << 7) + sw);
            f16x8 b2 = *(const f16x8*)(smem + BOFF + ((uint32_t)(64 + l31) << 7) + sw);
            accR = __builtin_amdgcn_mfma_f32_32x32x16_f16(a, b0, accR, 0, 0, 0);
            accZ = __builtin_amdgcn_mfma_f32_32x32x16_f16(a, b1, accZ, 0, 0, 0);
            accN = __builtin_amdgcn_mfma_f32_32x32x16_f16(a, b2, accN, 0, 0, 0);
        }
        if (t > 0) {
            // local out-dot for row xrow, dim xd over this chunk's 64 cols
            uint32_t slot = (uint32_t)(xrow >> 3);
            uint32_t rin = (uint32_t)(xrow & 7);
            const char* arow = smem + AOFF + slot * 1024 + rin * 128;
            const float* wp = (const float*)(smem + WOUT + (uint32_t)xd * 2048 + (uint32_t)kc * 256);
            int ro = (xrow >> 3) & 3;
            #pragma unroll
            for (int gg = 0; gg < 8; gg++) {
                int l = (gg + ro * 2) & 7;
                f16x8 hv = *(const f16x8*)(arow + ((uint32_t)(l ^ rin) << 4));
                const float4* wq = (const float4*)(wp + l * 8);
                float4 wa = wq[0], wb = wq[1];
                xacc += (float)hv[0]*wa.x + (float)hv[1]*wa.y + (float)hv[2]*wa.z + (float)hv[3]*wa.w
                      + (float)hv[4]*wb.x + (float)hv[5]*wb.y + (float)hv[6]*wb.z + (float)hv[7]*wb.w;
            }
        }
        __syncthreads();
    }

    // publish x_t (and write out_{t-1})
    {
        float v;
        if (t == 0) {
            v = xbuf[(size_t)(Mbase + xrow) * 2 + xd];
        } else {
            v = xacc + bo;
            if (by == 0) dout[((size_t)(Mbase + xrow) * 12 + (t - 1)) * 2 + xd] = v;
        }
        xs[xrow * 2 + xd] = v;
    }
    __syncthreads();

    // gate epilogue
    int jcg = Jbase + l31;
    const float4* pkp = (const float4*)(pk + (size_t)jcg * 12);
    float4 p0 = pkp[0], p1 = pkp[1], p2 = pkp[2];
    // p0={wxr0,wxr1,wxz0,wxz1} p1={wxn0,wxn1,bhr,bhz} p2={bhn,-,-,-}
    const _Float16* giR = gi16;
    const _Float16* giZ = gi16 + 2097152;
    const _Float16* giN = gi16 + 4194304;
    #pragma unroll
    for (int reg = 0; reg < 16; reg++) {
        int row = (reg & 3) + 8 * (reg >> 2) + 4 * half;
        int iloc = (w << 5) + row;
        size_t i = (size_t)Mbase + iloc;
        float g0 = (float)giR[i * 512 + jcg];
        float g1 = (float)giZ[i * 512 + jcg];
        float g2v = (float)giN[i * 512 + jcg];
        float x0 = xs[iloc * 2], x1 = xs[iloc * 2 + 1];
        float r = sigm_f(g0 + p0.x * x0 + p0.y * x1 + accR[reg] + p1.z);
        float u = sigm_f(g1 + p0.z * x0 + p0.w * x1 + accZ[reg] + p1.w);
        float nn = tanh_f(g2v + p1.x * x0 + p1.y * x1 + r * (accN[reg] + p2.x));
        float hold = (float)hin[i * 512 + jcg];
        float hn = (1.f - u) * nn + u * hold;
        hout[i * 512 + jcg] = (_Float16)hn;
    }
}

// ---------------- K3: out_11 = W_out @ h_12 + b_out (direct dot) ----------------
__global__ __launch_bounds__(256) void k3_final(
    const _Float16* __restrict__ h12, const float* __restrict__ W_out,
    const float* __restrict__ b_out, float* __restrict__ dout)
{
    __shared__ float wsh[1024];
    for (int i = threadIdx.x; i < 1024; i += 256) wsh[i] = W_out[i];
    __syncthreads();
    int i = blockIdx.x * 128 + (threadIdx.x >> 1), d = threadIdx.x & 1;
    const f16x8* hp = (const f16x8*)(h12 + (size_t)i * 512);
    const float* wp = wsh + d * 512;
    float s = 0.f;
    #pragma unroll 8
    for (int g = 0; g < 64; g++) {
        f16x8 hv = hp[g];
        #pragma unroll
        for (int e = 0; e < 8; e++) s += (float)hv[e] * wp[g * 8 + e];
    }
    dout[((size_t)i * 12 + 11) * 2 + d] = b_out[d] + s;
}

extern "C" void kernel_launch(void* const* d_in, const int* in_sizes, int n_in,
                              void* d_out, int out_size, void* d_ws, size_t ws_size,
                              hipStream_t stream)
{
    const float* z     = (const float*)d_in[0];
    const float* x     = (const float*)d_in[1];
    const float* x0    = (const float*)d_in[2];
    const float* W_ia  = (const float*)d_in[3];
    const float* b_ia  = (const float*)d_in[4];
    const float* W_h0  = (const float*)d_in[5];
    const float* b_h0  = (const float*)d_in[6];
    const float* W_ih  = (const float*)d_in[7];
    const float* b_ih  = (const float*)d_in[8];
    const float* W_hh  = (const float*)d_in[9];
    const float* b_hh  = (const float*)d_in[10];
    const float* W_out = (const float*)d_in[11];
    const float* b_out = (const float*)d_in[12];
    float* dout = (float*)d_out;

    char* ws = (char*)d_ws;
    _Float16* h16a   = (_Float16*)(ws + 0);          // 4 MiB
    _Float16* h16b   = (_Float16*)(ws + 4194304);    // 4 MiB
    _Float16* gi16   = (_Float16*)(ws + 8388608);    // 12 MiB
    _Float16* zx16   = (_Float16*)(ws + 20971520);   // 2 MiB
    _Float16* wcat16 = (_Float16*)(ws + 23068672);   // 1 MiB
    _Float16* whh16  = (_Float16*)(ws + 24117248);   // 1.5 MiB
    float*    pk     = (float*)(ws + 25690112);      // 24 KiB
    float*    xbuf   = (float*)(ws + 25714688);      // 32 KiB

    k0_prep<<<1024, 256, 0, stream>>>(z, x, x0, W_ia, b_ia, W_ih, W_hh, W_h0,
                                      W_out, b_hh, zx16, wcat16, whh16, pk, xbuf);
    k1_precompute<<<dim3(32, 32), 256, 0, stream>>>(zx16, wcat16, b_h0, b_ih, h16a, gi16);
    for (int t = 0; t < 12; t++) {
        _Float16* hin  = (t & 1) ? h16b : h16a;
        _Float16* hout = (t & 1) ? h16a : h16b;
        k2_step<<<dim3(32, 16), 256, 0, stream>>>(t, hin, hout, whh16, gi16,
                                                  pk, xbuf, W_out, b_out, dout);
    }
    k3_final<<<32, 256, 0, stream>>>((_Float16*)(ws + 0), W_out, b_out, dout);
}

// Round 7
// 308.572 us; speedup vs baseline: 1.1236x; 1.1236x over previous
//
#include <hip/hip_runtime.h>
#include <cstdint>
#include <cstddef>

// RNNDec GRU rollout: N=4096, H=512, T=12. R7 = R5 k2 (proven 295us) +
// vectorized k0 (R6) + direct-dot k3 (R6) + packed gi4 {r,z,n,pad} f16x4
// for coalesced epilogue loads. K-loop/tile/partial-exchange untouched.

typedef __attribute__((ext_vector_type(8))) _Float16 f16x8;
typedef __attribute__((ext_vector_type(4))) _Float16 f16x4;
typedef __attribute__((ext_vector_type(16))) float floatx16;

__device__ __forceinline__ float sigm_f(float v) { return 1.0f / (1.0f + __expf(-v)); }
__device__ __forceinline__ float tanh_f(float v) { return 2.0f / (1.0f + __expf(-2.0f * v)) - 1.0f; }

__device__ __forceinline__ void async16(void* lds, const void* g) {
    __builtin_amdgcn_global_load_lds(
        (const __attribute__((address_space(1))) void*)g,
        (__attribute__((address_space(3))) void*)lds, 16, 0, 0);
}

// ---------------- K0: casts + packing + a0 (vectorized) ----------------
__global__ __launch_bounds__(256) void k0_prep(
    const float* __restrict__ z, const float* __restrict__ x,
    const float* __restrict__ x0, const float* __restrict__ W_ia,
    const float* __restrict__ b_ia, const float* __restrict__ W_ih,
    const float* __restrict__ W_hh, const float* __restrict__ W_h0,
    const float* __restrict__ W_out, const float* __restrict__ b_hh,
    _Float16* __restrict__ zx16, _Float16* __restrict__ wcat16,
    _Float16* __restrict__ whh16, float* __restrict__ pk, float* __restrict__ xbuf)
{
    const int ZXV = 262144;            // 4096*256/4
    const int WCV = 131072;            // 2048*256/4
    const int WHV = 196608;            // 1536*512/4
    const int PKN = 512, XB = 8192;
    const int TOT = ZXV + WCV + WHV + PKN + XB;
    for (int g = blockIdx.x * 256 + threadIdx.x; g < TOT; g += gridDim.x * 256) {
        if (g < ZXV) {
            int i = g >> 6, k = (g & 63) << 2;
            float4 v = (k < 128) ? *(const float4*)(z + (size_t)i * 128 + k)
                                 : *(const float4*)(x + (size_t)i * 128 + (k - 128));
            f16x4 o = {(_Float16)v.x, (_Float16)v.y, (_Float16)v.z, (_Float16)v.w};
            *(f16x4*)(zx16 + (size_t)g * 4) = o;
        } else if (g < ZXV + WCV) {
            int j = (g - ZXV) << 2;
            int n = j >> 8, k = j & 255;
            float4 v;
            if (n < 512) {
                v = *(const float4*)(W_h0 + (size_t)n * 256 + k);
            } else {
                const float* p = W_ih + (size_t)(n - 512) * 258 + k;
                float2 a = *(const float2*)p, b = *(const float2*)(p + 2);
                v = make_float4(a.x, a.y, b.x, b.y);
            }
            f16x4 o = {(_Float16)v.x, (_Float16)v.y, (_Float16)v.z, (_Float16)v.w};
            *(f16x4*)(wcat16 + (size_t)j) = o;
        } else if (g < ZXV + WCV + WHV) {
            int j = (g - ZXV - WCV) << 2;
            float4 v = *(const float4*)(W_hh + (size_t)j);
            f16x4 o = {(_Float16)v.x, (_Float16)v.y, (_Float16)v.z, (_Float16)v.w};
            *(f16x4*)(whh16 + (size_t)j) = o;
        } else if (g < ZXV + WCV + WHV + PKN) {
            int jc = g - ZXV - WCV - WHV;
            float* o = pk + jc * 12;
            o[0] = W_ih[jc * 258 + 256];          o[1] = W_ih[jc * 258 + 257];
            o[2] = W_ih[(512 + jc) * 258 + 256];  o[3] = W_ih[(512 + jc) * 258 + 257];
            o[4] = W_ih[(1024 + jc) * 258 + 256]; o[5] = W_ih[(1024 + jc) * 258 + 257];
            o[6] = b_hh[jc]; o[7] = b_hh[512 + jc]; o[8] = b_hh[1024 + jc];
            o[9] = W_out[jc]; o[10] = W_out[512 + jc]; o[11] = 0.f;
        } else {
            int j = g - ZXV - WCV - WHV - PKN;
            int i = j >> 1, d = j & 1;
            float s = b_ia[d];
            #pragma unroll
            for (int k2 = 0; k2 < 4; k2++) s += x0[i * 4 + k2] * W_ia[d * 4 + k2];
            xbuf[j] = s;
        }
    }
}

// ---------------- K1: h0 (cols 0..511) + packed gi4 (cols 512..2047) ----------------
__global__ __launch_bounds__(256) void k1_precompute(
    const _Float16* __restrict__ zx16, const _Float16* __restrict__ wcat16,
    const float* __restrict__ b_h0, const float* __restrict__ b_ih,
    _Float16* __restrict__ h16a, _Float16* __restrict__ gi4)
{
    __shared__ __align__(16) char smem[24576];
    const uint32_t BOFF = 0, AOFF = 8192;
    int tid = threadIdx.x;
    int w = tid >> 6, lane = tid & 63;
    int half = lane >> 5, l31 = lane & 31;
    int rsub = lane >> 3, csub = lane & 7;
    int Mb = blockIdx.x * 128, Nb = blockIdx.y * 64;

    const _Float16* gsrc[6];
    uint32_t ldso[6];
    #pragma unroll
    for (int j = 0; j < 6; j++) {
        int L = w + 4 * j;
        if (L < 16) {
            int r = L * 8 + rsub;
            gsrc[j] = zx16 + (size_t)(Mb + r) * 256 + ((csub ^ (r & 7)) << 3);
            ldso[j] = AOFF + (uint32_t)L * 1024;
        } else {
            int rb = (L - 16) * 8 + rsub;
            gsrc[j] = wcat16 + (size_t)(Nb + rb) * 256 + ((csub ^ (rb & 7)) << 3);
            ldso[j] = BOFF + (uint32_t)(L - 16) * 1024;
        }
    }

    floatx16 acc0 = {0,0,0,0,0,0,0,0,0,0,0,0,0,0,0,0};
    floatx16 acc1 = {0,0,0,0,0,0,0,0,0,0,0,0,0,0,0,0};

    for (int kc = 0; kc < 4; kc++) {
        #pragma unroll
        for (int j = 0; j < 6; j++) async16(smem + ldso[j], gsrc[j] + kc * 64);
        __syncthreads();
        #pragma unroll
        for (int ks = 0; ks < 4; ks++) {
            int ch = ks * 2 + half;
            int ar = (w << 5) | l31;
            f16x8 a = *(const f16x8*)(smem + AOFF + ((uint32_t)ar << 7) + ((uint32_t)(ch ^ (ar & 7)) << 4));
            uint32_t sw = (uint32_t)(ch ^ (l31 & 7)) << 4;
            f16x8 b0 = *(const f16x8*)(smem + BOFF + ((uint32_t)l31 << 7) + sw);
            f16x8 b1 = *(const f16x8*)(smem + BOFF + ((uint32_t)(32 + l31) << 7) + sw);
            acc0 = __builtin_amdgcn_mfma_f32_32x32x16_f16(a, b0, acc0, 0, 0, 0);
            acc1 = __builtin_amdgcn_mfma_f32_32x32x16_f16(a, b1, acc1, 0, 0, 0);
        }
        __syncthreads();
    }

    #pragma unroll
    for (int nt = 0; nt < 2; nt++) {
        int ncol = Nb + nt * 32 + l31;
        floatx16 acc = nt ? acc1 : acc0;
        #pragma unroll
        for (int reg = 0; reg < 16; reg++) {
            int row = (reg & 3) + 8 * (reg >> 2) + 4 * half;
            size_t i = (size_t)Mb + (w << 5) + row;
            float v = acc[reg];
            if (ncol < 512) {
                h16a[i * 512 + ncol] = (_Float16)(v + b_h0[ncol]);
            } else {
                int c = ncol - 512;
                int g = c >> 9, jc = c & 511;
                gi4[(i * 512 + jc) * 4 + g] = (_Float16)(v + b_ih[c]);
            }
        }
    }
}

// ---------------- K2: one GRU step (R5 structure, packed gi4) ----------------
// Tile 128m x (32 jc x 3 gates). grid (32,16), 256 thr = 4 waves.
__global__ __launch_bounds__(256) void k2_step(
    int t,
    const _Float16* __restrict__ hin, _Float16* __restrict__ hout,
    const _Float16* __restrict__ whh16, const _Float16* __restrict__ gi4,
    const float* __restrict__ pk, const float* __restrict__ xbuf,
    float* __restrict__ partial, float* __restrict__ dout,
    const float* __restrict__ b_out)
{
    __shared__ __align__(16) char smem[46080];
    const uint32_t BOFF = 0, AOFF = 12288, PROD = 12288, XS = 45056;
    int tid = threadIdx.x;
    int bx = blockIdx.x, by = blockIdx.y;
    int Mbase = bx * 128, Jbase = by * 32;
    int w = tid >> 6, lane = tid & 63;
    int half = lane >> 5, l31 = lane & 31;
    int rsub = lane >> 3, csub = lane & 7;
    float* xs = (float*)(smem + XS);  // [128][2]

    // staging: A = 16 slots of 8 rows x 64 fp16; B = 12 slots (96 rows: g*32+jin)
    const _Float16* gsrc[7];
    uint32_t ldso[7];
    #pragma unroll
    for (int j = 0; j < 7; j++) {
        int L = w + 4 * j;   // 0..27
        if (L < 16) {
            int r = L * 8 + rsub;
            gsrc[j] = hin + (size_t)(Mbase + r) * 512 + ((csub ^ (r & 7)) << 3);
            ldso[j] = AOFF + (uint32_t)L * 1024;
        } else {
            int rb = (L - 16) * 8 + rsub;   // 0..95: rb = g*32 + jin
            int g = rb >> 5, jin = rb & 31;
            gsrc[j] = whh16 + (size_t)(g * 512 + Jbase + jin) * 512 + ((csub ^ (rb & 7)) << 3);
            ldso[j] = BOFF + (uint32_t)(L - 16) * 1024;
        }
    }

    // prologue: x_t for this block's 128 samples (and write out_{t-1})
    {
        int i = tid >> 1, d = tid & 1;
        float v;
        if (t == 0) {
            v = xbuf[(size_t)(Mbase + i) * 2 + d];
        } else {
            const float4* p = (const float4*)(partial + ((size_t)(Mbase + i) * 2 + d) * 16);
            float4 a = p[0], b = p[1], c = p[2], e = p[3];
            v = b_out[d] + a.x + a.y + a.z + a.w + b.x + b.y + b.z + b.w
                         + c.x + c.y + c.z + c.w + e.x + e.y + e.z + e.w;
            if (by == 0) dout[((size_t)(Mbase + i) * 12 + (t - 1)) * 2 + d] = v;
        }
        xs[i * 2 + d] = v;
    }

    floatx16 accR = {0,0,0,0,0,0,0,0,0,0,0,0,0,0,0,0};
    floatx16 accZ = {0,0,0,0,0,0,0,0,0,0,0,0,0,0,0,0};
    floatx16 accN = {0,0,0,0,0,0,0,0,0,0,0,0,0,0,0,0};

    for (int kc = 0; kc < 8; kc++) {
        #pragma unroll
        for (int j = 0; j < 7; j++) async16(smem + ldso[j], gsrc[j] + kc * 64);
        __syncthreads();
        #pragma unroll
        for (int ks = 0; ks < 4; ks++) {
            int ch = ks * 2 + half;
            int ar = (w << 5) | l31;
            f16x8 a = *(const f16x8*)(smem + AOFF + ((uint32_t)ar << 7) + ((uint32_t)(ch ^ (ar & 7)) << 4));
            uint32_t sw = (uint32_t)(ch ^ (l31 & 7)) << 4;
            f16x8 b0 = *(const f16x8*)(smem + BOFF + ((uint32_t)l31 << 7) + sw);
            f16x8 b1 = *(const f16x8*)(smem + BOFF + ((uint32_t)(32 + l31) << 7) + sw);
            f16x8 b2 = *(const f16x8*)(smem + BOFF + ((uint32_t)(64 + l31) << 7) + sw);
            accR = __builtin_amdgcn_mfma_f32_32x32x16_f16(a, b0, accR, 0, 0, 0);
            accZ = __builtin_amdgcn_mfma_f32_32x32x16_f16(a, b1, accZ, 0, 0, 0);
            accN = __builtin_amdgcn_mfma_f32_32x32x16_f16(a, b2, accN, 0, 0, 0);
        }
        __syncthreads();
    }

    // epilogue: gates + state update; out-partials in LDS (reuse A/B region)
    float* prod = (float*)(smem + PROD);  // [128][32][2] fp32 = 32 KB
    int jcg = Jbase + l31;
    const float4* pkp = (const float4*)(pk + (size_t)jcg * 12);
    float4 p0 = pkp[0], p1 = pkp[1], p2 = pkp[2];
    // p0={wxr0,wxr1,wxz0,wxz1} p1={wxn0,wxn1,bhr,bhz} p2={bhn,wo0,wo1,-}
    const f16x4* gi4p = (const f16x4*)gi4;
    #pragma unroll
    for (int reg = 0; reg < 16; reg++) {
        int row = (reg & 3) + 8 * (reg >> 2) + 4 * half;
        int iloc = (w << 5) + row;
        size_t i = (size_t)Mbase + iloc;
        f16x4 gv = gi4p[i * 512 + jcg];
        float g0 = (float)gv[0], g1 = (float)gv[1], g2v = (float)gv[2];
        float x0 = xs[iloc * 2], x1 = xs[iloc * 2 + 1];
        float r = sigm_f(g0 + p0.x * x0 + p0.y * x1 + accR[reg] + p1.z);
        float u = sigm_f(g1 + p0.z * x0 + p0.w * x1 + accZ[reg] + p1.w);
        float nn = tanh_f(g2v + p1.x * x0 + p1.y * x1 + r * (accN[reg] + p2.x));
        float hold = (float)hin[i * 512 + jcg];
        float hn = (1.f - u) * nn + u * hold;
        hout[i * 512 + jcg] = (_Float16)hn;
        ((float2*)prod)[iloc * 32 + l31] = make_float2(hn * p2.y, hn * p2.z);
    }
    __syncthreads();
    {
        int i = tid >> 1, d = tid & 1;
        float s = 0.f;
        #pragma unroll
        for (int jj = 0; jj < 32; jj++) {
            int jc = (jj + i) & 31;   // skew to avoid bank conflicts
            s += prod[(i * 32 + jc) * 2 + d];
        }
        partial[((size_t)(Mbase + i) * 2 + d) * 16 + by] = s;
    }
}

// ---------------- K3: out_11 = W_out @ h_12 + b_out (direct dot) ----------------
__global__ __launch_bounds__(256) void k3_final(
    const _Float16* __restrict__ h12, const float* __restrict__ W_out,
    const float* __restrict__ b_out, float* __restrict__ dout)
{
    __shared__ float wsh[1024];
    for (int i = threadIdx.x; i < 1024; i += 256) wsh[i] = W_out[i];
    __syncthreads();
    int i = blockIdx.x * 128 + (threadIdx.x >> 1), d = threadIdx.x & 1;
    const f16x8* hp = (const f16x8*)(h12 + (size_t)i * 512);
    const float* wp = wsh + d * 512;
    float s = 0.f;
    #pragma unroll 8
    for (int g = 0; g < 64; g++) {
        f16x8 hv = hp[g];
        #pragma unroll
        for (int e = 0; e < 8; e++) s += (float)hv[e] * wp[g * 8 + e];
    }
    dout[((size_t)i * 12 + 11) * 2 + d] = b_out[d] + s;
}

extern "C" void kernel_launch(void* const* d_in, const int* in_sizes, int n_in,
                              void* d_out, int out_size, void* d_ws, size_t ws_size,
                              hipStream_t stream)
{
    const float* z     = (const float*)d_in[0];
    const float* x     = (const float*)d_in[1];
    const float* x0    = (const float*)d_in[2];
    const float* W_ia  = (const float*)d_in[3];
    const float* b_ia  = (const float*)d_in[4];
    const float* W_h0  = (const float*)d_in[5];
    const float* b_h0  = (const float*)d_in[6];
    const float* W_ih  = (const float*)d_in[7];
    const float* b_ih  = (const float*)d_in[8];
    const float* W_hh  = (const float*)d_in[9];
    const float* b_hh  = (const float*)d_in[10];
    const float* W_out = (const float*)d_in[11];
    const float* b_out = (const float*)d_in[12];
    float* dout = (float*)d_out;

    char* ws = (char*)d_ws;
    _Float16* h16a   = (_Float16*)(ws + 0);          // 4 MiB
    _Float16* h16b   = (_Float16*)(ws + 4194304);    // 4 MiB
    _Float16* gi4    = (_Float16*)(ws + 8388608);    // 4096*512*4 f16 = 16 MiB
    _Float16* zx16   = (_Float16*)(ws + 25165824);   // 2 MiB
    _Float16* wcat16 = (_Float16*)(ws + 27262976);   // 1 MiB
    _Float16* whh16  = (_Float16*)(ws + 28311552);   // 1.5 MiB
    float*    pk     = (float*)(ws + 29884416);      // 24 KiB
    float*    xbuf   = (float*)(ws + 29908992);      // 32 KiB
    float*    partial= (float*)(ws + 29941760);      // 512 KiB

    k0_prep<<<1024, 256, 0, stream>>>(z, x, x0, W_ia, b_ia, W_ih, W_hh, W_h0,
                                      W_out, b_hh, zx16, wcat16, whh16, pk, xbuf);
    k1_precompute<<<dim3(32, 32), 256, 0, stream>>>(zx16, wcat16, b_h0, b_ih, h16a, gi4);
    for (int t = 0; t < 12; t++) {
        _Float16* hin  = (t & 1) ? h16b : h16a;
        _Float16* hout = (t & 1) ? h16a : h16b;
        k2_step<<<dim3(32, 16), 256, 0, stream>>>(t, hin, hout, whh16, gi4,
                                                  pk, xbuf, partial, dout, b_out);
    }
    k3_final<<<32, 256, 0, stream>>>(h16a, W_out, b_out, dout);
}